// Round 5
// baseline (232.986 us; speedup 1.0000x reference)
//
#include <hip/hip_runtime.h>

// MHA: B=4, S=1024, D=1024, H=16, DK=64
// prep (cvt+mask[b][kt][q]) -> fused QKV GEMM (XCD-swizzled, global-swizzled
// global_load_lds) -> flash attn: double-buffered LDS K/V, combo-major XCD
// swizzle, KV-split x2, S^T trick, 32 q-rows/wave, cvt_pk P-pack, setprio
// around MFMA -> out GEMM with FUSED merge ((O0+O1)*inv staged into As).

typedef __attribute__((ext_vector_type(8))) short short8;
typedef __attribute__((ext_vector_type(4))) float f32x4;
typedef __attribute__((ext_vector_type(4))) unsigned short u16x4;
typedef unsigned short u16;
typedef unsigned long long u64;

#define SCALE_Q 0.180336880f  // 0.125 * log2(e); folded into Q at projection

__device__ __forceinline__ u16 f2bf(float f) {  // RNE
    unsigned u = __float_as_uint(f);
    return (u16)((u + 0x7FFFu + ((u >> 16) & 1u)) >> 16);
}
__device__ __forceinline__ float bf2f(u16 v) {
    return __uint_as_float((unsigned)v << 16);
}

// async global->LDS, 16B per lane; LDS dest is wave-uniform base + lane*16
__device__ __forceinline__ void gl_lds16(const u16* g, u16* l) {
    __builtin_amdgcn_global_load_lds(
        (__attribute__((address_space(1))) void*)g,
        (__attribute__((address_space(3))) void*)l, 16, 0, 0);
}

// ---------------- fused prep: 7x f32->bf16 cvt + mask->bits ----------------
__global__ __launch_bounds__(256) void prep(
    const float* __restrict__ q, const float* __restrict__ k,
    const float* __restrict__ v, const float* __restrict__ wq,
    const float* __restrict__ wk, const float* __restrict__ wv,
    const float* __restrict__ wo, const int* __restrict__ mask,
    u16* __restrict__ xq, u16* __restrict__ xk, u16* __restrict__ xv,
    u16* __restrict__ wqb, u16* __restrict__ wkb, u16* __restrict__ wvb,
    u16* __restrict__ wob, u64* __restrict__ bits) {
    int bid = blockIdx.x;
    if (bid < 16384) {
        const float* src; u16* dst; int i;
        if (bid < 12288) {
            int chunk = bid >> 12;
            int off = bid & 4095;
            src = (chunk == 0) ? q : ((chunk == 1) ? k : v);
            dst = (chunk == 0) ? xq : ((chunk == 1) ? xk : xv);
            i = off * 256 + threadIdx.x;
        } else {
            int wb = bid - 12288;
            int chunk = wb >> 10;
            int off = wb & 1023;
            src = (chunk == 0) ? wq : ((chunk == 1) ? wk : ((chunk == 2) ? wv : wo));
            dst = (chunk == 0) ? wqb : ((chunk == 1) ? wkb : ((chunk == 2) ? wvb : wob));
            i = off * 256 + threadIdx.x;
        }
        f32x4 val = ((const f32x4*)src)[i];
        u16x4 r;
        r.x = f2bf(val.x); r.y = f2bf(val.y); r.z = f2bf(val.z); r.w = f2bf(val.w);
        ((u16x4*)dst)[i] = r;
    } else {
        int mb = bid - 16384;   // 0..4095
        int wid = threadIdx.x >> 6, lane = threadIdx.x & 63;
        int base = mb * 1024 + wid * 256;
        int b = mb >> 10, qrow = mb & 1023;
        #pragma unroll
        for (int j = 0; j < 4; ++j) {
            u64 bal = __ballot(mask[base + j * 64 + lane] != 0);
            int kt = wid * 4 + j;
            if (lane == 0) bits[(size_t)(b * 16 + kt) * 1024 + qrow] = bal;  // [b][kt][q]
        }
    }
}

// ---------------- fused QKV projection GEMM (128x128, swizzled staging) -----
__global__ __launch_bounds__(256, 3) void gemm_qkv(
    const u16* __restrict__ Aq, const u16* __restrict__ Ak, const u16* __restrict__ Av,
    const u16* __restrict__ Wq, const u16* __restrict__ Wk, const u16* __restrict__ Wv,
    const float* __restrict__ bq, const float* __restrict__ bk, const float* __restrict__ bv,
    u16* __restrict__ Qo, u16* __restrict__ Ko, u16* __restrict__ VTo) {
    __shared__ __align__(16) u16 As[128 * 64];
    __shared__ __align__(16) u16 Bs[128 * 64];
    const int bid = blockIdx.x;
    const int id = (bid & 7) * 96 + (bid >> 3);   // bijective, n0 = bid&7
    const int n0 = (id / 96) * 128;
    const int pm = id % 96;
    const int p = pm >> 5;
    const int m0 = (pm & 31) * 128;
    const u16* A = (p == 0) ? Aq : ((p == 1) ? Ak : Av);
    const u16* W = (p == 0) ? Wq : ((p == 1) ? Wk : Wv);
    const float* bias = (p == 0) ? bq : ((p == 1) ? bk : bv);

    const int t = threadIdx.x;
    const int lane = t & 63;
    const int wid = t >> 6;
    const int l15 = lane & 15;
    const int quad = lane >> 4;
    const int wm = (wid & 1) * 64;
    const int wn = (wid >> 1) * 64;
    const int r8 = lane >> 3, gr = lane & 7;
    const int gsw = (gr ^ r8) * 8;   // swizzled global granule offset

    f32x4 acc[4][4];
    #pragma unroll
    for (int i = 0; i < 4; ++i)
        #pragma unroll
        for (int j = 0; j < 4; ++j) acc[i][j] = (f32x4){0.f, 0.f, 0.f, 0.f};

    for (int kt = 0; kt < 1024; kt += 64) {
        __syncthreads();
        #pragma unroll
        for (int c = 0; c < 8; ++c) {
            int call = wid * 8 + c;
            if (call < 16) {
                int rb = call * 8;
                gl_lds16(&A[(size_t)(m0 + rb + r8) * 1024 + kt + gsw], &As[rb * 64]);
            } else {
                int rb = (call - 16) * 8;
                gl_lds16(&W[(size_t)(n0 + rb + r8) * 1024 + kt + gsw], &Bs[rb * 64]);
            }
        }
        __syncthreads();
        #pragma unroll
        for (int ks = 0; ks < 2; ++ks) {
            short8 af[4], bf[4];
            #pragma unroll
            for (int i = 0; i < 4; ++i) {
                int mr = wm + i * 16 + l15;
                af[i] = *(const short8*)&As[mr * 64 + (((ks << 2) + quad) ^ (mr & 7)) * 8];
                int nr = wn + i * 16 + l15;
                bf[i] = *(const short8*)&Bs[nr * 64 + (((ks << 2) + quad) ^ (nr & 7)) * 8];
            }
            #pragma unroll
            for (int mi = 0; mi < 4; ++mi)
                #pragma unroll
                for (int ni = 0; ni < 4; ++ni)
                    acc[mi][ni] = __builtin_amdgcn_mfma_f32_16x16x32_bf16(
                        af[mi], bf[ni], acc[mi][ni], 0, 0, 0);
        }
    }

    u16* dst01 = (p == 0) ? Qo : Ko;
    const float qs = (p == 0) ? SCALE_Q : 1.0f;
    #pragma unroll
    for (int mi = 0; mi < 4; ++mi) {
        #pragma unroll
        for (int ni = 0; ni < 4; ++ni) {
            int col = n0 + wn + ni * 16 + l15;  // 0..1023
            int h = col >> 6, dk = col & 63;
            float bcol = bias[col];
            if (p < 2) {
                #pragma unroll
                for (int r = 0; r < 4; ++r) {
                    int row = m0 + wm + mi * 16 + quad * 4 + r;
                    int bb = row >> 10, s = row & 1023;
                    dst01[(size_t)((bb * 16 + h) * 1024 + s) * 64 + dk] =
                        f2bf((acc[mi][ni][r] + bcol) * qs);
                }
            } else {
                int row0 = m0 + wm + mi * 16 + quad * 4;
                int bb = row0 >> 10, s0 = row0 & 1023;
                u64 pk = 0;
                #pragma unroll
                for (int r = 0; r < 4; ++r)
                    pk |= (u64)f2bf(acc[mi][ni][r] + bcol) << (16 * r);
                *(u64*)&VTo[(size_t)((bb * 16 + h) * 64 + dk) * 1024 + s0] = pk;
            }
        }
    }
}

// ---------------- output projection GEMM with FUSED merge -------------------
// A-tile = (O0+O1)*inv staged in registers (coalesced 16B/lane, merge, then
// ds_write_b128 at slot ag^(row&7) — same XOR layout the read path expects;
// conflict-free since the 8 lanes sharing ag hit 8 distinct slots). inv is
// uniform per K-step (h = kt>>6). B (Wo) stays on the async gl_lds16 path.
__global__ __launch_bounds__(256, 3) void gemm_out(
    const u16* __restrict__ O0, const u16* __restrict__ O1,
    const float* __restrict__ Lb, const u16* __restrict__ Wo,
    const float* __restrict__ bo, float* __restrict__ out) {
    __shared__ __align__(16) u16 As[64 * 64];
    __shared__ __align__(16) u16 Bs[128 * 64];
    const int bid = blockIdx.x;
    const int id = (bid & 7) * 64 + (bid >> 3);   // bijective, n0 = bid&7
    const int n0 = (id >> 6) * 128;
    const int m0 = (id & 63) * 64;
    const int t = threadIdx.x;
    const int lane = t & 63;
    const int wid = t >> 6;
    const int l15 = lane & 15;
    const int quad = lane >> 4;
    const int wm = (wid & 1) * 32;
    const int wn = (wid >> 1) * 64;
    const int r8 = lane >> 3, gr = lane & 7;
    const int gsw = (gr ^ r8) * 8;
    const int ar = t >> 3;     // A-merge: row within 32-row half (0..31)
    const int ag = t & 7;      // A-merge: global granule 0..7 (coalesced)

    f32x4 acc[2][4];
    #pragma unroll
    for (int i = 0; i < 2; ++i)
        #pragma unroll
        for (int j = 0; j < 4; ++j) acc[i][j] = (f32x4){0.f, 0.f, 0.f, 0.f};

    for (int kt = 0; kt < 1024; kt += 64) {
        __syncthreads();
        // B staging: async DMA, 4 calls/wave cover 128 rows
        #pragma unroll
        for (int c = 0; c < 4; ++c) {
            int rb = (wid * 4 + c) * 8;
            gl_lds16(&Wo[(size_t)(n0 + rb + r8) * 1024 + kt + gsw], &Bs[rb * 64]);
        }
        // A staging fused with merge: (O0+O1) * 1/(L0+L1), bf16, swizzled slot
        {
            const int hh = kt >> 6;
            #pragma unroll
            for (int c = 0; c < 2; ++c) {
                int row = c * 32 + ar;
                int grow = m0 + row;
                size_t goff = (size_t)grow * 1024 + kt + ag * 8;
                short8 o0 = *(const short8*)&O0[goff];
                short8 o1 = *(const short8*)&O1[goff];
                size_t li = (size_t)(((grow >> 10) * 16 + hh) * 1024) + (grow & 1023);
                float inv = 1.0f / (Lb[li] + Lb[65536 + li]);
                unsigned pw[4];
                #pragma unroll
                for (int j = 0; j < 4; ++j) {
                    float x0 = (bf2f((u16)o0[2 * j]) + bf2f((u16)o1[2 * j])) * inv;
                    float x1 = (bf2f((u16)o0[2 * j + 1]) + bf2f((u16)o1[2 * j + 1])) * inv;
                    asm("v_cvt_pk_bf16_f32 %0, %1, %2" : "=v"(pw[j]) : "v"(x0), "v"(x1));
                }
                int slot = ag ^ (row & 7);
                *(f32x4*)&As[row * 64 + slot * 8] = *(f32x4*)pw;
            }
        }
        __syncthreads();
        #pragma unroll
        for (int ks = 0; ks < 2; ++ks) {
            short8 af[2], bf[4];
            #pragma unroll
            for (int i = 0; i < 2; ++i) {
                int mr = wm + i * 16 + l15;
                af[i] = *(const short8*)&As[mr * 64 + (((ks << 2) + quad) ^ (mr & 7)) * 8];
            }
            #pragma unroll
            for (int j = 0; j < 4; ++j) {
                int nr = wn + j * 16 + l15;
                bf[j] = *(const short8*)&Bs[nr * 64 + (((ks << 2) + quad) ^ (nr & 7)) * 8];
            }
            #pragma unroll
            for (int mi = 0; mi < 2; ++mi)
                #pragma unroll
                for (int ni = 0; ni < 4; ++ni)
                    acc[mi][ni] = __builtin_amdgcn_mfma_f32_16x16x32_bf16(
                        af[mi], bf[ni], acc[mi][ni], 0, 0, 0);
        }
    }

    #pragma unroll
    for (int mi = 0; mi < 2; ++mi) {
        #pragma unroll
        for (int ni = 0; ni < 4; ++ni) {
            int col = n0 + wn + ni * 16 + l15;
            float bcol = bo[col];
            #pragma unroll
            for (int r = 0; r < 4; ++r) {
                int row = m0 + wm + mi * 16 + quad * 4 + r;
                out[(size_t)row * 1024 + col] = acc[mi][ni][r] + bcol;
            }
        }
    }
}

// ---------------- flash attention: double-buffered LDS, 1 barrier/tile ------
// 1D grid 1024, combo-major XCD swizzle: work = (bid%8)*128 + bid/8, so each
// XCD's resident blocks share 16 (b,h,half)-combos -> KV panels L2-hot.
// K/V double-buffered: stage tile kt+1 right AFTER the single per-iter barrier
// so the global_load_lds ops have the whole compute phase to land. setprio(1)
// around both MFMA clusters (T5): favors MFMA-phase waves over staging waves
// of the other resident blocks.
__device__ __forceinline__ void stage_kv(const u16* Kh, const u16* Vh, int kv0,
                                         u16* KsB, u16* VsB, int wid, int r8, int gsw) {
    #pragma unroll
    for (int c = 0; c < 4; ++c) {
        int call = wid * 4 + c;
        if (call < 8) {
            int rb = call * 8;
            gl_lds16(&Kh[(size_t)(kv0 + rb + r8) * 64 + gsw], &KsB[rb * 64]);
        } else {
            int db = (call - 8) * 8;
            gl_lds16(&Vh[(size_t)(db + r8) * 1024 + kv0 + gsw], &VsB[db * 64]);
        }
    }
}

__global__ __launch_bounds__(256) void attn_kernel(
    const u16* __restrict__ Q, const u16* __restrict__ K, const u16* __restrict__ VT,
    const u64* __restrict__ mbits, u16* __restrict__ O, float* __restrict__ L) {
    __shared__ __align__(16) u16 Ks[2][64 * 64];
    __shared__ __align__(16) u16 Vs[2][64 * 64];
    __shared__ __align__(16) u16 Ps[4][32 * 72];  // per-wave P [q_local][kv], stride 72

    const int bid = blockIdx.x;
    const int work = (bid & 7) * 128 + (bid >> 3);
    const int qt = work & 7;
    const int combo = work >> 3;          // 0..127
    const int h = combo & 15;
    const int bh = combo >> 4;            // b*2 + half
    const int b = bh >> 1;
    const int half = bh & 1;

    const int t = threadIdx.x;
    const int lane = t & 63;
    const int wid = t >> 6;
    const int l15 = lane & 15;
    const int quad = lane >> 4;
    const int qw = qt * 128 + wid * 32;   // first q row of this wave
    const int ktg0 = half * 8;            // first global kv tile of this half
    const int r8 = lane >> 3, gr = lane & 7;
    const int gsw = (gr ^ r8) * 8;        // pre-swizzled global granule offset

    const size_t headoff = (size_t)(b * 16 + h) * 1024 * 64;
    const u16* Qh = Q + headoff;
    const u16* Kh = K + headoff;
    const u16* Vh = VT + headoff;  // [64][1024]

    // Q fragments in registers for both 16-row groups; same mapping for
    // A- and B-frags, so the S^T operand swap needs no load changes.
    short8 qf[2][2];
    #pragma unroll
    for (int g = 0; g < 2; ++g)
        #pragma unroll
        for (int ks = 0; ks < 2; ++ks)
            qf[g][ks] = *(const short8*)&Qh[(size_t)(qw + g * 16 + l15) * 64 + ks * 32 + quad * 8];

    f32x4 o_acc[2][4];
    #pragma unroll
    for (int g = 0; g < 2; ++g)
        #pragma unroll
        for (int j = 0; j < 4; ++j) o_acc[g][j] = (f32x4){0.f, 0.f, 0.f, 0.f};
    float lacc[2] = {0.f, 0.f};   // per-lane: q = l15 (per group), this lane's kv subset

    // transposed mask [b][kt][q]: one u64 per tile per group for this lane's q-row
    const u64* mp = &mbits[(size_t)(b * 16 + ktg0) * 1024 + qw + l15];

    // prologue: stage first tile into buffer 0
    stage_kv(Kh, Vh, ktg0 * 64, Ks[0], Vs[0], wid, r8, gsw);

    for (int kt = 0; kt < 8; ++kt) {
        __syncthreads();   // vmcnt drain: buf[cur] staged; all waves done with buf[cur^1]
        const int cur = kt & 1;
        if (kt < 7)
            stage_kv(Kh, Vh, (ktg0 + kt + 1) * 64, Ks[cur ^ 1], Vs[cur ^ 1], wid, r8, gsw);
        const u16* Kc = Ks[cur];
        const u16* Vc = Vs[cur];

        // mask words for both q-groups (issued early; consumed at softmax)
        u64 w0 = mp[0];
        u64 w1 = mp[16];

        // S^T = K Q^T : sacc[g][mi] rows kv=mi*16+quad*4+r, col q=l15 (group g)
        f32x4 sacc[2][4];
        #pragma unroll
        for (int g = 0; g < 2; ++g)
            #pragma unroll
            for (int j = 0; j < 4; ++j) sacc[g][j] = (f32x4){0.f, 0.f, 0.f, 0.f};
        __builtin_amdgcn_s_setprio(1);
        #pragma unroll
        for (int ks = 0; ks < 2; ++ks) {
            #pragma unroll
            for (int mi = 0; mi < 4; ++mi) {
                int n = mi * 16 + l15;
                short8 kf = *(const short8*)&Kc[n * 64 + (((ks << 2) + quad) ^ (n & 7)) * 8];
                sacc[0][mi] = __builtin_amdgcn_mfma_f32_16x16x32_bf16(kf, qf[0][ks], sacc[0][mi], 0, 0, 0);
                sacc[1][mi] = __builtin_amdgcn_mfma_f32_16x16x32_bf16(kf, qf[1][ks], sacc[1][mi], 0, 0, 0);
            }
        }
        __builtin_amdgcn_s_setprio(0);

        // masked exp2; cvt_pk packs 2 f32 -> u32 of 2 bf16 (RNE), b64 store
        #pragma unroll
        for (int g = 0; g < 2; ++g) {
            u64 w = g ? w1 : w0;
            unsigned t0 = (unsigned)(w >> (quad * 4));
            unsigned t1 = (unsigned)(w >> (quad * 4 + 32));
            #pragma unroll
            for (int mi = 0; mi < 4; ++mi) {
                unsigned sel = (mi & 2) ? t1 : t0;
                sel >>= (mi & 1) * 16;
                float p0 = __builtin_amdgcn_exp2f(sacc[g][mi][0]);
                float p1 = __builtin_amdgcn_exp2f(sacc[g][mi][1]);
                float p2 = __builtin_amdgcn_exp2f(sacc[g][mi][2]);
                float p3 = __builtin_amdgcn_exp2f(sacc[g][mi][3]);
                p0 = (sel & 1u) ? p0 : 0.f;
                p1 = (sel & 2u) ? p1 : 0.f;
                p2 = (sel & 4u) ? p2 : 0.f;
                p3 = (sel & 8u) ? p3 : 0.f;
                lacc[g] += p0; lacc[g] += p1; lacc[g] += p2; lacc[g] += p3;
                unsigned pw0, pw1;
                asm("v_cvt_pk_bf16_f32 %0, %1, %2" : "=v"(pw0) : "v"(p0), "v"(p1));
                asm("v_cvt_pk_bf16_f32 %0, %1, %2" : "=v"(pw1) : "v"(p2), "v"(p3));
                *(u64*)&Ps[wid][(g * 16 + l15) * 72 + mi * 16 + quad * 4] =
                    (u64)pw0 | ((u64)pw1 << 32);
            }
        }

        // O += P V (P per-wave LDS A-layout; V^T B-layout); vf shared by groups
        __builtin_amdgcn_s_setprio(1);
        #pragma unroll
        for (int ks = 0; ks < 2; ++ks) {
            short8 pf0 = *(const short8*)&Ps[wid][(size_t)l15 * 72 + ks * 32 + quad * 8];
            short8 pf1 = *(const short8*)&Ps[wid][(size_t)(16 + l15) * 72 + ks * 32 + quad * 8];
            #pragma unroll
            for (int j = 0; j < 4; ++j) {
                int d = j * 16 + l15;
                short8 vf = *(const short8*)&Vc[d * 64 + (((ks << 2) + quad) ^ (d & 7)) * 8];
                o_acc[0][j] = __builtin_amdgcn_mfma_f32_16x16x32_bf16(pf0, vf, o_acc[0][j], 0, 0, 0);
                o_acc[1][j] = __builtin_amdgcn_mfma_f32_16x16x32_bf16(pf1, vf, o_acc[1][j], 0, 0, 0);
            }
        }
        __builtin_amdgcn_s_setprio(0);

        mp += 1024;   // next kv tile's mask words
    }

    // reduce l across the 4 lanes sharing q=l15 (per group), store partials
    u16* Oh = O + (size_t)half * 4194304;
    float* Lh = L + (size_t)half * 65536;
    #pragma unroll
    for (int g = 0; g < 2; ++g) {
        float l = lacc[g];
        l += __shfl_xor(l, 16);
        l += __shfl_xor(l, 32);
        if (lane < 16)
            Lh[(size_t)(b * 16 + h) * 1024 + qw + g * 16 + lane] = l;
        #pragma unroll
        for (int r = 0; r < 4; ++r) {
            int qrow = qw + g * 16 + quad * 4 + r;   // o_acc row (C-layout)
            #pragma unroll
            for (int ni = 0; ni < 4; ++ni) {
                Oh[(size_t)(b * 1024 + qrow) * 1024 + h * 64 + ni * 16 + l15] =
                    f2bf(o_acc[g][ni][r]);
            }
        }
    }
}

// ---------------- launch ----------------
extern "C" void kernel_launch(void* const* d_in, const int* in_sizes, int n_in,
                              void* d_out, int out_size, void* d_ws, size_t ws_size,
                              hipStream_t stream) {
    const float* query = (const float*)d_in[0];
    const float* key_ = (const float*)d_in[1];
    const float* value = (const float*)d_in[2];
    const int* mask = (const int*)d_in[3];
    const float* wq = (const float*)d_in[4];
    const float* bq = (const float*)d_in[5];
    const float* wk = (const float*)d_in[6];
    const float* bk = (const float*)d_in[7];
    const float* wv = (const float*)d_in[8];
    const float* bv = (const float*)d_in[9];
    const float* wo = (const float*)d_in[10];
    const float* bo = (const float*)d_in[11];
    float* out = (float*)d_out;

    char* ws = (char*)d_ws;
    const size_t XB = (size_t)4096 * 1024 * 2;  // 8 MB bf16 activation
    const size_t WB = (size_t)1024 * 1024 * 2;  // 2 MB bf16 weight
    u16* xq = (u16*)(ws);
    u16* xk = (u16*)(ws + XB);        // after qkv: O-half 0
    u16* xv = (u16*)(ws + 2 * XB);    // after qkv: O-half 1
    u16* wqb = (u16*)(ws + 3 * XB);
    u16* wkb = (u16*)(ws + 3 * XB + WB);
    u16* wvb = (u16*)(ws + 3 * XB + 2 * WB);
    u16* wob = (u16*)(ws + 3 * XB + 3 * WB);
    u16* Qb = (u16*)(ws + 3 * XB + 4 * WB);
    u16* Kb = (u16*)(ws + 4 * XB + 4 * WB);
    u16* VTb = (u16*)(ws + 5 * XB + 4 * WB);
    u64* bits = (u64*)(ws + 6 * XB + 4 * WB);
    float* Lbuf = (float*)(ws + 6 * XB + 4 * WB + (512 << 10));
    u16* Opart = xk;    // 16 MB spanning xk+xv (dead after gemm_qkv)

    prep<<<20480, 256, 0, stream>>>(query, key_, value, wq, wk, wv, wo, mask,
                                    xq, xk, xv, wqb, wkb, wvb, wob, bits);
    gemm_qkv<<<768, 256, 0, stream>>>(xq, xk, xv, wqb, wkb, wvb,
                                      bq, bk, bv, Qb, Kb, VTb);
    attn_kernel<<<1024, 256, 0, stream>>>(Qb, Kb, VTb, bits, Opart, Lbuf);
    gemm_out<<<512, 256, 0, stream>>>(Opart, Opart + 4194304, Lbuf, wob, bo, out);
}

// Round 6
// 226.860 us; speedup vs baseline: 1.0270x; 1.0270x over previous
//
#include <hip/hip_runtime.h>

// MHA: B=4, S=1024, D=1024, H=16, DK=64
// prep (cvt+mask[b][kt][q]) -> fused QKV GEMM (natural block order: A-tile
// sharers land on one XCD by residue, A fetched once globally) -> flash attn:
// double-buffered LDS K/V (stage-after-barrier), combo-major XCD swizzle,
// KV-split x2, S^T trick, 32 q-rows/wave, cvt_pk P-pack -> merge -> out GEMM.

typedef __attribute__((ext_vector_type(8))) short short8;
typedef __attribute__((ext_vector_type(4))) float f32x4;
typedef __attribute__((ext_vector_type(4))) unsigned short u16x4;
typedef unsigned short u16;
typedef unsigned long long u64;

#define SCALE_Q 0.180336880f  // 0.125 * log2(e); folded into Q at projection

__device__ __forceinline__ u16 f2bf(float f) {  // RNE
    unsigned u = __float_as_uint(f);
    return (u16)((u + 0x7FFFu + ((u >> 16) & 1u)) >> 16);
}
__device__ __forceinline__ float bf2f(u16 v) {
    return __uint_as_float((unsigned)v << 16);
}

// async global->LDS, 16B per lane; LDS dest is wave-uniform base + lane*16
__device__ __forceinline__ void gl_lds16(const u16* g, u16* l) {
    __builtin_amdgcn_global_load_lds(
        (__attribute__((address_space(1))) void*)g,
        (__attribute__((address_space(3))) void*)l, 16, 0, 0);
}

// ---------------- fused prep: 7x f32->bf16 cvt + mask->bits ----------------
__global__ __launch_bounds__(256) void prep(
    const float* __restrict__ q, const float* __restrict__ k,
    const float* __restrict__ v, const float* __restrict__ wq,
    const float* __restrict__ wk, const float* __restrict__ wv,
    const float* __restrict__ wo, const int* __restrict__ mask,
    u16* __restrict__ xq, u16* __restrict__ xk, u16* __restrict__ xv,
    u16* __restrict__ wqb, u16* __restrict__ wkb, u16* __restrict__ wvb,
    u16* __restrict__ wob, u64* __restrict__ bits) {
    int bid = blockIdx.x;
    if (bid < 16384) {
        const float* src; u16* dst; int i;
        if (bid < 12288) {
            int chunk = bid >> 12;
            int off = bid & 4095;
            src = (chunk == 0) ? q : ((chunk == 1) ? k : v);
            dst = (chunk == 0) ? xq : ((chunk == 1) ? xk : xv);
            i = off * 256 + threadIdx.x;
        } else {
            int wb = bid - 12288;
            int chunk = wb >> 10;
            int off = wb & 1023;
            src = (chunk == 0) ? wq : ((chunk == 1) ? wk : ((chunk == 2) ? wv : wo));
            dst = (chunk == 0) ? wqb : ((chunk == 1) ? wkb : ((chunk == 2) ? wvb : wob));
            i = off * 256 + threadIdx.x;
        }
        f32x4 val = ((const f32x4*)src)[i];
        u16x4 r;
        r.x = f2bf(val.x); r.y = f2bf(val.y); r.z = f2bf(val.z); r.w = f2bf(val.w);
        ((u16x4*)dst)[i] = r;
    } else {
        int mb = bid - 16384;   // 0..4095
        int wid = threadIdx.x >> 6, lane = threadIdx.x & 63;
        int base = mb * 1024 + wid * 256;
        int b = mb >> 10, qrow = mb & 1023;
        #pragma unroll
        for (int j = 0; j < 4; ++j) {
            u64 bal = __ballot(mask[base + j * 64 + lane] != 0);
            int kt = wid * 4 + j;
            if (lane == 0) bits[(size_t)(b * 16 + kt) * 1024 + qrow] = bal;  // [b][kt][q]
        }
    }
}

// ---------------- fused QKV projection GEMM (128x128, swizzled staging) -----
// Natural block order: the 8 blocks sharing an A-tile (all n0) have the same
// blockIdx%8 residue (96%8==0, 32%8==0) -> same XCD -> A fetched ONCE
// globally (~24MB), W re-fetched per XCD (~48MB). Do NOT "XCD-swizzle" this
// grid: measured FETCH 101MB (+10us) when each XCD owned an n0-panel.
__global__ __launch_bounds__(256, 3) void gemm_qkv(
    const u16* __restrict__ Aq, const u16* __restrict__ Ak, const u16* __restrict__ Av,
    const u16* __restrict__ Wq, const u16* __restrict__ Wk, const u16* __restrict__ Wv,
    const float* __restrict__ bq, const float* __restrict__ bk, const float* __restrict__ bv,
    u16* __restrict__ Qo, u16* __restrict__ Ko, u16* __restrict__ VTo) {
    __shared__ __align__(16) u16 As[128 * 64];
    __shared__ __align__(16) u16 Bs[128 * 64];
    const int id = blockIdx.x;
    const int n0 = (id / 96) * 128;
    const int pm = id % 96;
    const int p = pm >> 5;
    const int m0 = (pm & 31) * 128;
    const u16* A = (p == 0) ? Aq : ((p == 1) ? Ak : Av);
    const u16* W = (p == 0) ? Wq : ((p == 1) ? Wk : Wv);
    const float* bias = (p == 0) ? bq : ((p == 1) ? bk : bv);

    const int t = threadIdx.x;
    const int lane = t & 63;
    const int wid = t >> 6;
    const int l15 = lane & 15;
    const int quad = lane >> 4;
    const int wm = (wid & 1) * 64;
    const int wn = (wid >> 1) * 64;
    const int r8 = lane >> 3, gr = lane & 7;
    const int gsw = (gr ^ r8) * 8;   // swizzled global granule offset

    f32x4 acc[4][4];
    #pragma unroll
    for (int i = 0; i < 4; ++i)
        #pragma unroll
        for (int j = 0; j < 4; ++j) acc[i][j] = (f32x4){0.f, 0.f, 0.f, 0.f};

    for (int kt = 0; kt < 1024; kt += 64) {
        __syncthreads();
        #pragma unroll
        for (int c = 0; c < 8; ++c) {
            int call = wid * 8 + c;
            if (call < 16) {
                int rb = call * 8;
                gl_lds16(&A[(size_t)(m0 + rb + r8) * 1024 + kt + gsw], &As[rb * 64]);
            } else {
                int rb = (call - 16) * 8;
                gl_lds16(&W[(size_t)(n0 + rb + r8) * 1024 + kt + gsw], &Bs[rb * 64]);
            }
        }
        __syncthreads();
        #pragma unroll
        for (int ks = 0; ks < 2; ++ks) {
            short8 af[4], bf[4];
            #pragma unroll
            for (int i = 0; i < 4; ++i) {
                int mr = wm + i * 16 + l15;
                af[i] = *(const short8*)&As[mr * 64 + (((ks << 2) + quad) ^ (mr & 7)) * 8];
                int nr = wn + i * 16 + l15;
                bf[i] = *(const short8*)&Bs[nr * 64 + (((ks << 2) + quad) ^ (nr & 7)) * 8];
            }
            #pragma unroll
            for (int mi = 0; mi < 4; ++mi)
                #pragma unroll
                for (int ni = 0; ni < 4; ++ni)
                    acc[mi][ni] = __builtin_amdgcn_mfma_f32_16x16x32_bf16(
                        af[mi], bf[ni], acc[mi][ni], 0, 0, 0);
        }
    }

    u16* dst01 = (p == 0) ? Qo : Ko;
    const float qs = (p == 0) ? SCALE_Q : 1.0f;
    #pragma unroll
    for (int mi = 0; mi < 4; ++mi) {
        #pragma unroll
        for (int ni = 0; ni < 4; ++ni) {
            int col = n0 + wn + ni * 16 + l15;  // 0..1023
            int h = col >> 6, dk = col & 63;
            float bcol = bias[col];
            if (p < 2) {
                #pragma unroll
                for (int r = 0; r < 4; ++r) {
                    int row = m0 + wm + mi * 16 + quad * 4 + r;
                    int bb = row >> 10, s = row & 1023;
                    dst01[(size_t)((bb * 16 + h) * 1024 + s) * 64 + dk] =
                        f2bf((acc[mi][ni][r] + bcol) * qs);
                }
            } else {
                int row0 = m0 + wm + mi * 16 + quad * 4;
                int bb = row0 >> 10, s0 = row0 & 1023;
                u64 pk = 0;
                #pragma unroll
                for (int r = 0; r < 4; ++r)
                    pk |= (u64)f2bf(acc[mi][ni][r] + bcol) << (16 * r);
                *(u64*)&VTo[(size_t)((bb * 16 + h) * 64 + dk) * 1024 + s0] = pk;
            }
        }
    }
}

// ---------------- output projection GEMM (64x128, swizzled staging) ---------
// Natural block order (same residue argument: 64%8==0 -> X-tile sharers on
// one XCD, X fetched once).
__global__ __launch_bounds__(256, 3) void gemm_out(
    const u16* __restrict__ X, const u16* __restrict__ Wo,
    const float* __restrict__ bo, float* __restrict__ out) {
    __shared__ __align__(16) u16 As[64 * 64];
    __shared__ __align__(16) u16 Bs[128 * 64];
    const int id = blockIdx.x;
    const int n0 = (id >> 6) * 128;
    const int m0 = (id & 63) * 64;
    const int t = threadIdx.x;
    const int lane = t & 63;
    const int wid = t >> 6;
    const int l15 = lane & 15;
    const int quad = lane >> 4;
    const int wm = (wid & 1) * 32;
    const int wn = (wid >> 1) * 64;
    const int r8 = lane >> 3, gr = lane & 7;
    const int gsw = (gr ^ r8) * 8;

    f32x4 acc[2][4];
    #pragma unroll
    for (int i = 0; i < 2; ++i)
        #pragma unroll
        for (int j = 0; j < 4; ++j) acc[i][j] = (f32x4){0.f, 0.f, 0.f, 0.f};

    for (int kt = 0; kt < 1024; kt += 64) {
        __syncthreads();
        #pragma unroll
        for (int c = 0; c < 6; ++c) {
            int call = wid * 6 + c;
            if (call < 8) {
                int rb = call * 8;
                gl_lds16(&X[(size_t)(m0 + rb + r8) * 1024 + kt + gsw], &As[rb * 64]);
            } else {
                int rb = (call - 8) * 8;
                gl_lds16(&Wo[(size_t)(n0 + rb + r8) * 1024 + kt + gsw], &Bs[rb * 64]);
            }
        }
        __syncthreads();
        #pragma unroll
        for (int ks = 0; ks < 2; ++ks) {
            short8 af[2], bf[4];
            #pragma unroll
            for (int i = 0; i < 2; ++i) {
                int mr = wm + i * 16 + l15;
                af[i] = *(const short8*)&As[mr * 64 + (((ks << 2) + quad) ^ (mr & 7)) * 8];
            }
            #pragma unroll
            for (int j = 0; j < 4; ++j) {
                int nr = wn + j * 16 + l15;
                bf[j] = *(const short8*)&Bs[nr * 64 + (((ks << 2) + quad) ^ (nr & 7)) * 8];
            }
            #pragma unroll
            for (int mi = 0; mi < 2; ++mi)
                #pragma unroll
                for (int ni = 0; ni < 4; ++ni)
                    acc[mi][ni] = __builtin_amdgcn_mfma_f32_16x16x32_bf16(
                        af[mi], bf[ni], acc[mi][ni], 0, 0, 0);
        }
    }

    #pragma unroll
    for (int mi = 0; mi < 2; ++mi) {
        #pragma unroll
        for (int ni = 0; ni < 4; ++ni) {
            int col = n0 + wn + ni * 16 + l15;
            float bcol = bo[col];
            #pragma unroll
            for (int r = 0; r < 4; ++r) {
                int row = m0 + wm + mi * 16 + quad * 4 + r;
                out[(size_t)row * 1024 + col] = acc[mi][ni][r] + bcol;
            }
        }
    }
}

// ---------------- flash attention: double-buffered LDS, 1 barrier/tile ------
// 1D grid 1024, combo-major XCD swizzle: work = (bid%8)*128 + bid/8, so each
// XCD's resident blocks share 16 (b,h,half)-combos -> KV panels L2-hot
// (measured: FETCH 70MB -> 16.7MB). K/V double-buffered: stage tile kt+1
// right AFTER the single per-iter barrier so the global_load_lds ops have the
// whole compute phase to land. No setprio: 4-wave lockstep structure is the
// m190 null regime.
__device__ __forceinline__ void stage_kv(const u16* Kh, const u16* Vh, int kv0,
                                         u16* KsB, u16* VsB, int wid, int r8, int gsw) {
    #pragma unroll
    for (int c = 0; c < 4; ++c) {
        int call = wid * 4 + c;
        if (call < 8) {
            int rb = call * 8;
            gl_lds16(&Kh[(size_t)(kv0 + rb + r8) * 64 + gsw], &KsB[rb * 64]);
        } else {
            int db = (call - 8) * 8;
            gl_lds16(&Vh[(size_t)(db + r8) * 1024 + kv0 + gsw], &VsB[db * 64]);
        }
    }
}

__global__ __launch_bounds__(256) void attn_kernel(
    const u16* __restrict__ Q, const u16* __restrict__ K, const u16* __restrict__ VT,
    const u64* __restrict__ mbits, u16* __restrict__ O, float* __restrict__ L) {
    __shared__ __align__(16) u16 Ks[2][64 * 64];
    __shared__ __align__(16) u16 Vs[2][64 * 64];
    __shared__ __align__(16) u16 Ps[4][32 * 72];  // per-wave P [q_local][kv], stride 72

    const int bid = blockIdx.x;
    const int work = (bid & 7) * 128 + (bid >> 3);
    const int qt = work & 7;
    const int combo = work >> 3;          // 0..127
    const int h = combo & 15;
    const int bh = combo >> 4;            // b*2 + half
    const int b = bh >> 1;
    const int half = bh & 1;

    const int t = threadIdx.x;
    const int lane = t & 63;
    const int wid = t >> 6;
    const int l15 = lane & 15;
    const int quad = lane >> 4;
    const int qw = qt * 128 + wid * 32;   // first q row of this wave
    const int ktg0 = half * 8;            // first global kv tile of this half
    const int r8 = lane >> 3, gr = lane & 7;
    const int gsw = (gr ^ r8) * 8;        // pre-swizzled global granule offset

    const size_t headoff = (size_t)(b * 16 + h) * 1024 * 64;
    const u16* Qh = Q + headoff;
    const u16* Kh = K + headoff;
    const u16* Vh = VT + headoff;  // [64][1024]

    // Q fragments in registers for both 16-row groups; same mapping for
    // A- and B-frags, so the S^T operand swap needs no load changes.
    short8 qf[2][2];
    #pragma unroll
    for (int g = 0; g < 2; ++g)
        #pragma unroll
        for (int ks = 0; ks < 2; ++ks)
            qf[g][ks] = *(const short8*)&Qh[(size_t)(qw + g * 16 + l15) * 64 + ks * 32 + quad * 8];

    f32x4 o_acc[2][4];
    #pragma unroll
    for (int g = 0; g < 2; ++g)
        #pragma unroll
        for (int j = 0; j < 4; ++j) o_acc[g][j] = (f32x4){0.f, 0.f, 0.f, 0.f};
    float lacc[2] = {0.f, 0.f};   // per-lane: q = l15 (per group), this lane's kv subset

    // transposed mask [b][kt][q]: one u64 per tile per group for this lane's q-row
    const u64* mp = &mbits[(size_t)(b * 16 + ktg0) * 1024 + qw + l15];

    // prologue: stage first tile into buffer 0
    stage_kv(Kh, Vh, ktg0 * 64, Ks[0], Vs[0], wid, r8, gsw);

    for (int kt = 0; kt < 8; ++kt) {
        __syncthreads();   // vmcnt drain: buf[cur] staged; all waves done with buf[cur^1]
        const int cur = kt & 1;
        if (kt < 7)
            stage_kv(Kh, Vh, (ktg0 + kt + 1) * 64, Ks[cur ^ 1], Vs[cur ^ 1], wid, r8, gsw);
        const u16* Kc = Ks[cur];
        const u16* Vc = Vs[cur];

        // mask words for both q-groups (issued early; consumed at softmax)
        u64 w0 = mp[0];
        u64 w1 = mp[16];

        // S^T = K Q^T : sacc[g][mi] rows kv=mi*16+quad*4+r, col q=l15 (group g)
        f32x4 sacc[2][4];
        #pragma unroll
        for (int g = 0; g < 2; ++g)
            #pragma unroll
            for (int j = 0; j < 4; ++j) sacc[g][j] = (f32x4){0.f, 0.f, 0.f, 0.f};
        #pragma unroll
        for (int ks = 0; ks < 2; ++ks) {
            #pragma unroll
            for (int mi = 0; mi < 4; ++mi) {
                int n = mi * 16 + l15;
                short8 kf = *(const short8*)&Kc[n * 64 + (((ks << 2) + quad) ^ (n & 7)) * 8];
                sacc[0][mi] = __builtin_amdgcn_mfma_f32_16x16x32_bf16(kf, qf[0][ks], sacc[0][mi], 0, 0, 0);
                sacc[1][mi] = __builtin_amdgcn_mfma_f32_16x16x32_bf16(kf, qf[1][ks], sacc[1][mi], 0, 0, 0);
            }
        }

        // masked exp2; cvt_pk packs 2 f32 -> u32 of 2 bf16 (RNE), b64 store
        #pragma unroll
        for (int g = 0; g < 2; ++g) {
            u64 w = g ? w1 : w0;
            unsigned t0 = (unsigned)(w >> (quad * 4));
            unsigned t1 = (unsigned)(w >> (quad * 4 + 32));
            #pragma unroll
            for (int mi = 0; mi < 4; ++mi) {
                unsigned sel = (mi & 2) ? t1 : t0;
                sel >>= (mi & 1) * 16;
                float p0 = __builtin_amdgcn_exp2f(sacc[g][mi][0]);
                float p1 = __builtin_amdgcn_exp2f(sacc[g][mi][1]);
                float p2 = __builtin_amdgcn_exp2f(sacc[g][mi][2]);
                float p3 = __builtin_amdgcn_exp2f(sacc[g][mi][3]);
                p0 = (sel & 1u) ? p0 : 0.f;
                p1 = (sel & 2u) ? p1 : 0.f;
                p2 = (sel & 4u) ? p2 : 0.f;
                p3 = (sel & 8u) ? p3 : 0.f;
                lacc[g] += p0; lacc[g] += p1; lacc[g] += p2; lacc[g] += p3;
                unsigned pw0, pw1;
                asm("v_cvt_pk_bf16_f32 %0, %1, %2" : "=v"(pw0) : "v"(p0), "v"(p1));
                asm("v_cvt_pk_bf16_f32 %0, %1, %2" : "=v"(pw1) : "v"(p2), "v"(p3));
                *(u64*)&Ps[wid][(g * 16 + l15) * 72 + mi * 16 + quad * 4] =
                    (u64)pw0 | ((u64)pw1 << 32);
            }
        }

        // O += P V (P per-wave LDS A-layout; V^T B-layout); vf shared by groups
        #pragma unroll
        for (int ks = 0; ks < 2; ++ks) {
            short8 pf0 = *(const short8*)&Ps[wid][(size_t)l15 * 72 + ks * 32 + quad * 8];
            short8 pf1 = *(const short8*)&Ps[wid][(size_t)(16 + l15) * 72 + ks * 32 + quad * 8];
            #pragma unroll
            for (int j = 0; j < 4; ++j) {
                int d = j * 16 + l15;
                short8 vf = *(const short8*)&Vc[d * 64 + (((ks << 2) + quad) ^ (d & 7)) * 8];
                o_acc[0][j] = __builtin_amdgcn_mfma_f32_16x16x32_bf16(pf0, vf, o_acc[0][j], 0, 0, 0);
                o_acc[1][j] = __builtin_amdgcn_mfma_f32_16x16x32_bf16(pf1, vf, o_acc[1][j], 0, 0, 0);
            }
        }

        mp += 1024;   // next kv tile's mask words
    }

    // reduce l across the 4 lanes sharing q=l15 (per group), store partials
    u16* Oh = O + (size_t)half * 4194304;
    float* Lh = L + (size_t)half * 65536;
    #pragma unroll
    for (int g = 0; g < 2; ++g) {
        float l = lacc[g];
        l += __shfl_xor(l, 16);
        l += __shfl_xor(l, 32);
        if (lane < 16)
            Lh[(size_t)(b * 16 + h) * 1024 + qw + g * 16 + lane] = l;
        #pragma unroll
        for (int r = 0; r < 4; ++r) {
            int qrow = qw + g * 16 + quad * 4 + r;   // o_acc row (C-layout)
            #pragma unroll
            for (int ni = 0; ni < 4; ++ni) {
                Oh[(size_t)(b * 1024 + qrow) * 1024 + h * 64 + ni * 16 + l15] =
                    f2bf(o_acc[g][ni][r]);
            }
        }
    }
}

// ---------------- merge: X = (o0 + o1) / (l0 + l1), bf16 out ----------------
__global__ __launch_bounds__(256) void merge_halves(
    const u16* __restrict__ O, const float* __restrict__ L, u16* __restrict__ X) {
    int i = (blockIdx.x * 256 + threadIdx.x) * 8;   // elem index, 8 per thread
    int b = i >> 20, s = (i >> 10) & 1023, c = i & 1023, h = c >> 6;
    short8 o0 = *(const short8*)&O[i];
    short8 o1 = *(const short8*)&O[4194304 + i];
    size_t li = (size_t)(b * 16 + h) * 1024 + s;
    float inv = 1.0f / (L[li] + L[65536 + li]);
    short8 r;
    #pragma unroll
    for (int j = 0; j < 8; ++j) {
        float x = (bf2f((u16)o0[j]) + bf2f((u16)o1[j])) * inv;
        r[j] = (short)f2bf(x);
    }
    *(short8*)&X[i] = r;
}

// ---------------- launch ----------------
extern "C" void kernel_launch(void* const* d_in, const int* in_sizes, int n_in,
                              void* d_out, int out_size, void* d_ws, size_t ws_size,
                              hipStream_t stream) {
    const float* query = (const float*)d_in[0];
    const float* key_ = (const float*)d_in[1];
    const float* value = (const float*)d_in[2];
    const int* mask = (const int*)d_in[3];
    const float* wq = (const float*)d_in[4];
    const float* bq = (const float*)d_in[5];
    const float* wk = (const float*)d_in[6];
    const float* bk = (const float*)d_in[7];
    const float* wv = (const float*)d_in[8];
    const float* bv = (const float*)d_in[9];
    const float* wo = (const float*)d_in[10];
    const float* bo = (const float*)d_in[11];
    float* out = (float*)d_out;

    char* ws = (char*)d_ws;
    const size_t XB = (size_t)4096 * 1024 * 2;  // 8 MB bf16 activation
    const size_t WB = (size_t)1024 * 1024 * 2;  // 2 MB bf16 weight
    u16* xq = (u16*)(ws);
    u16* xk = (u16*)(ws + XB);        // after qkv: O-half 0
    u16* xv = (u16*)(ws + 2 * XB);    // after qkv: O-half 1
    u16* wqb = (u16*)(ws + 3 * XB);
    u16* wkb = (u16*)(ws + 3 * XB + WB);
    u16* wvb = (u16*)(ws + 3 * XB + 2 * WB);
    u16* wob = (u16*)(ws + 3 * XB + 3 * WB);
    u16* Qb = (u16*)(ws + 3 * XB + 4 * WB);
    u16* Kb = (u16*)(ws + 4 * XB + 4 * WB);
    u16* VTb = (u16*)(ws + 5 * XB + 4 * WB);
    u64* bits = (u64*)(ws + 6 * XB + 4 * WB);
    float* Lbuf = (float*)(ws + 6 * XB + 4 * WB + (512 << 10));
    u16* Opart = xk;    // 16 MB spanning xk+xv (dead after gemm_qkv)
    u16* Xattn = xq;    // xq dead after gemm_qkv

    prep<<<20480, 256, 0, stream>>>(query, key_, value, wq, wk, wv, wo, mask,
                                    xq, xk, xv, wqb, wkb, wvb, wob, bits);
    gemm_qkv<<<768, 256, 0, stream>>>(xq, xk, xv, wqb, wkb, wvb,
                                      bq, bk, bv, Qb, Kb, VTb);
    attn_kernel<<<1024, 256, 0, stream>>>(Qb, Kb, VTb, bits, Opart, Lbuf);
    merge_halves<<<2048, 256, 0, stream>>>(Opart, Lbuf, Xattn);
    gemm_out<<<512, 256, 0, stream>>>(Xattn, wob, bo, out);
}